// Round 10
// baseline (625.651 us; speedup 1.0000x reference)
//
#include <hip/hip_runtime.h>
#include <math.h>

#define D_MODEL 768
#define D_INNER 1536
#define D_STATE 16
#define D_CONV 4
#define DT_RANK 48
#define N_LAYER 3
#define BATCH 2
#define SEQLEN 1024
#define NROWS (BATCH * SEQLEN)   // 2048
#define XDBL_W (DT_RANK + 2 * D_STATE)  // 80
#define EPS 1e-5f

#define SCLEN 16
#define SDN 16                   // d-channels per scan block

typedef short bf16x8 __attribute__((ext_vector_type(8)));
typedef float f32x4 __attribute__((ext_vector_type(4)));

__device__ __forceinline__ ushort f2bf(float x) {
    union { float f; uint u; } v; v.f = x;
    uint r = v.u + 0x7fff + ((v.u >> 16) & 1);   // RNE
    return (ushort)(r >> 16);
}
__device__ __forceinline__ float bf2f(ushort x) {
    union { uint u; float f; } v; v.u = ((uint)x) << 16;
    return v.f;
}

__device__ __forceinline__ void gload_lds16(const void* g, void* l) {
    __builtin_amdgcn_global_load_lds(
        (const __attribute__((address_space(1))) unsigned int*)g,
        (__attribute__((address_space(3))) unsigned int*)l, 16, 0, 0);
}

// ---------------- all weight conversions in ONE dispatch ----------------
#define CVT_N0 (3 * 3072 * 768 / 4)
#define CVT_N1 (3 * 768 * 1536 / 4)
#define CVT_N2 (3 * 128 * 1536 / 4)
#define CVT_N3 (3 * 1536 * 64 / 4)
#define CVT_C1 (CVT_N0)
#define CVT_C2 (CVT_C1 + CVT_N1)
#define CVT_C3 (CVT_C2 + CVT_N2)
#define CVT_TOT (CVT_C3 + CVT_N3)

__global__ __launch_bounds__(256) void cvt_all_kernel(
    const float* __restrict__ w_in, const float* __restrict__ w_out,
    const float* __restrict__ w_x, const float* __restrict__ w_dt,
    ushort* __restrict__ d_in, ushort* __restrict__ d_out,
    ushort* __restrict__ d_x, ushort* __restrict__ d_dt)
{
    int i = blockIdx.x * 256 + threadIdx.x;
    if (i < CVT_C1) {
        float4 v = ((const float4*)w_in)[i];
        ushort4 o; o.x = f2bf(v.x); o.y = f2bf(v.y); o.z = f2bf(v.z); o.w = f2bf(v.w);
        ((ushort4*)d_in)[i] = o;
    } else if (i < CVT_C2) {
        int j = i - CVT_C1;
        float4 v = ((const float4*)w_out)[j];
        ushort4 o; o.x = f2bf(v.x); o.y = f2bf(v.y); o.z = f2bf(v.z); o.w = f2bf(v.w);
        ((ushort4*)d_out)[j] = o;
    } else if (i < CVT_C3) {
        int j = i - CVT_C2;
        const int per = 128 * 1536 / 4;
        int li = j / per, rem = j - li * per;
        int r = (rem * 4) / 1536, c = (rem * 4) % 1536;
        ushort4 o = make_ushort4(0, 0, 0, 0);
        if (r < XDBL_W) {
            const float* s = w_x + ((size_t)li * XDBL_W + r) * 1536 + c;
            o.x = f2bf(s[0]); o.y = f2bf(s[1]); o.z = f2bf(s[2]); o.w = f2bf(s[3]);
        }
        ((ushort4*)d_x)[j] = o;
    } else if (i < CVT_TOT) {
        int j = i - CVT_C3;
        const int per = 1536 * 64 / 4;
        int li = j / per, rem = j - li * per;
        int r = (rem * 4) / 64, c = (rem * 4) % 64;
        ushort4 o = make_ushort4(0, 0, 0, 0);
        if (c < DT_RANK) {
            const float* s = w_dt + ((size_t)li * 1536 + r) * DT_RANK + c;
            o.x = f2bf(s[0]); o.y = f2bf(s[1]); o.z = f2bf(s[2]); o.w = f2bf(s[3]);
        }
        ((ushort4*)d_dt)[j] = o;
    }
}

// ---------------- add + rmsnorm ----------------
__global__ __launch_bounds__(256) void add_rmsnorm_kernel(
    const float* __restrict__ x, const float* __restrict__ res_in,
    const float* __restrict__ w, float* __restrict__ res_out,
    float* __restrict__ normed_f32, ushort* __restrict__ normed_bf)
{
    int row = blockIdx.x;
    int tid = threadIdx.x;
    const float* xr = x + row * D_MODEL;
    float v[3];
    float ss = 0.f;
#pragma unroll
    for (int i = 0; i < 3; i++) {
        int c = tid + i * 256;
        float t = xr[c];
        if (res_in) t += res_in[row * D_MODEL + c];
        v[i] = t;
        ss += t * t;
    }
    for (int off = 32; off; off >>= 1) ss += __shfl_xor(ss, off, 64);
    __shared__ float red[4];
    if ((tid & 63) == 0) red[tid >> 6] = ss;
    __syncthreads();
    float tot = red[0] + red[1] + red[2] + red[3];
    float scale = rsqrtf(tot * (1.f / D_MODEL) + EPS);
#pragma unroll
    for (int i = 0; i < 3; i++) {
        int c = tid + i * 256;
        if (res_out) res_out[row * D_MODEL + c] = v[i];
        float o = v[i] * scale * w[c];
        if (normed_f32) normed_f32[row * D_MODEL + c] = o;
        if (normed_bf)  normed_bf[row * D_MODEL + c] = f2bf(o);
    }
}

// ---------------- bf16 MFMA GEMM: C[M,N] = A[M,K] @ W[N,K]^T ----------------
// EPI: 0 none (f32 or bf16 out per OUTBF), 1 softplus(acc+bias[n]) f32 out.
template <int BM, int BN, int EPI, int OUTBF>
__global__ __launch_bounds__(256) void gemm_mfma_kernel(
    const ushort* __restrict__ A, const ushort* __restrict__ W,
    const float* __restrict__ bias, void* __restrict__ Cv,
    int ldc, int Nout, int M, int K)
{
    constexpr int TM = BM / 32;
    constexpr int TN = BN / 32;
    __shared__ __attribute__((aligned(16))) ushort As[BM * 64];
    __shared__ __attribute__((aligned(16))) ushort Ws[BN * 64];
    const int t = threadIdx.x;
    const int lane = t & 63, w = t >> 6;
    const int ln15 = lane & 15, q = lane >> 4;
    const int row0 = blockIdx.y * BM, col0 = blockIdx.x * BN;
    const int wm0 = (w & 1) * (BM / 2), wn0 = (w >> 1) * (BN / 2);

    float* Cf = (float*)Cv;
    ushort* Cb = (ushort*)Cv;

    f32x4 acc[TM][TN];
#pragma unroll
    for (int i = 0; i < TM; i++)
#pragma unroll
        for (int j = 0; j < TN; j++) acc[i][j] = (f32x4){0.f, 0.f, 0.f, 0.f};

    for (int k0 = 0; k0 < K; k0 += 64) {
        __syncthreads();
#pragma unroll
        for (int i = 0; i < BM / 32; i++) {
            int p = (i * 4 + w) * 64 + lane;
            int r = p >> 3, s = p & 7;
            int g = s ^ (r & 7);
            gload_lds16(A + (size_t)(row0 + r) * K + k0 + g * 8, &As[p * 8]);
        }
#pragma unroll
        for (int i = 0; i < BN / 32; i++) {
            int p = (i * 4 + w) * 64 + lane;
            int r = p >> 3, s = p & 7;
            int g = s ^ (r & 7);
            gload_lds16(W + (size_t)(col0 + r) * K + k0 + g * 8, &Ws[p * 8]);
        }
        __syncthreads();
#pragma unroll
        for (int ks = 0; ks < 2; ks++) {
            bf16x8 af[TM], wf[TN];
#pragma unroll
            for (int im = 0; im < TM; im++) {
                int m = wm0 + im * 16 + ln15;
                int slot = (ks * 4 + q) ^ (m & 7);
                af[im] = *(const bf16x8*)&As[m * 64 + slot * 8];
            }
#pragma unroll
            for (int jn = 0; jn < TN; jn++) {
                int n = wn0 + jn * 16 + ln15;
                int slot = (ks * 4 + q) ^ (n & 7);
                wf[jn] = *(const bf16x8*)&Ws[n * 64 + slot * 8];
            }
#pragma unroll
            for (int im = 0; im < TM; im++)
#pragma unroll
                for (int jn = 0; jn < TN; jn++)
                    acc[im][jn] = __builtin_amdgcn_mfma_f32_16x16x32_bf16(
                        af[im], wf[jn], acc[im][jn], 0, 0, 0);
        }
    }
#pragma unroll
    for (int im = 0; im < TM; im++) {
#pragma unroll
        for (int jn = 0; jn < TN; jn++) {
            int rr = row0 + wm0 + im * 16 + q * 4;
            int cc = col0 + wn0 + jn * 16 + ln15;
            if (cc < Nout) {
#pragma unroll
                for (int r = 0; r < 4; r++) {
                    float v = acc[im][jn][r];
                    if (EPI == 1) {
                        v += bias[cc];
                        v = (v > 20.f) ? v : log1pf(__expf(v));
                    }
                    if (OUTBF) Cb[(size_t)(rr + r) * ldc + cc] = f2bf(v);
                    else       Cf[(size_t)(rr + r) * ldc + cc] = v;
                }
            }
        }
    }
}

// ---------------- x_proj GEMM with fused conv+SiLU on the A side -----------
// BM=32 rows (l), BN=128 cols (xdbl, pad), K=1536 (d). A[r][k] =
// silu(conv(xz-x[r-3..r][k])). Stages raw x with 3-row halo into LDS, computes
// conv into the XOR-swizzled As layout, then the standard MFMA loop.
// Dual epilogue: f32 xdbl (cc<80) + bf16 xdt (cc<48, zeros 48..63).
__global__ __launch_bounds__(256) void xproj_conv_kernel(
    const ushort* __restrict__ xzbf, const ushort* __restrict__ W,
    const float* __restrict__ cw, const float* __restrict__ cb,
    float* __restrict__ xdbl, ushort* __restrict__ xdt)
{
    __shared__ __attribute__((aligned(16))) ushort Xs[35 * 64];  // raw halo tile
    __shared__ __attribute__((aligned(16))) ushort As[32 * 64];  // swizzled conv out
    __shared__ __attribute__((aligned(16))) ushort Ws[128 * 64];
    __shared__ float cwS[64 * 4];
    __shared__ float cbS[64];
    const int t = threadIdx.x;
    const int lane = t & 63, w = t >> 6;
    const int ln15 = lane & 15, q = lane >> 4;
    const int row0 = blockIdx.y * 32;
    const bool halo_valid = (row0 & 1023) != 0;   // tile never straddles batch
    const int wm0 = (w & 1) * 16, wn0 = (w >> 1) * 64;

    f32x4 acc[4];
#pragma unroll
    for (int j = 0; j < 4; j++) acc[j] = (f32x4){0.f, 0.f, 0.f, 0.f};

    for (int k0 = 0; k0 < D_INNER; k0 += 64) {
        __syncthreads();
        // stage raw x halo tile: rows row0-3 .. row0+31, cols k0..k0+63
        for (int it = t; it < 35 * 16; it += 256) {
            int r = it >> 4, cq = it & 15;
            int gr = row0 - 3 + r;
            ushort4 v = make_ushort4(0, 0, 0, 0);
            if (r >= 3 || halo_valid)
                v = *(const ushort4*)&xzbf[(size_t)gr * (2 * D_INNER) + k0 + cq * 4];
            *(ushort4*)&Xs[r * 64 + cq * 4] = v;
        }
        // stage conv weights for this k-chunk
        cwS[t] = cw[k0 * 4 + t];                 // 256 floats = 64 d x 4 taps
        if (t < 64) cbS[t] = cb[k0 + t];
        // stage W (async, swizzled source)
#pragma unroll
        for (int i = 0; i < 4; i++) {
            int p = (i * 4 + w) * 64 + lane;
            int r = p >> 3, s = p & 7;
            int g = s ^ (r & 7);
            gload_lds16(W + (size_t)r * D_INNER + k0 + g * 8, &Ws[p * 8]);
        }
        __syncthreads();
        // compute As = silu(conv) in swizzled layout: thread (r,g) -> 1 granule
        {
            int r = t >> 3, g = t & 7;
            ushort out[8];
#pragma unroll
            for (int e = 0; e < 8; e++) {
                int col = g * 8 + e;
                float s = cbS[col];
                s += cwS[col * 4 + 0] * bf2f(Xs[(r + 0) * 64 + col]);
                s += cwS[col * 4 + 1] * bf2f(Xs[(r + 1) * 64 + col]);
                s += cwS[col * 4 + 2] * bf2f(Xs[(r + 2) * 64 + col]);
                s += cwS[col * 4 + 3] * bf2f(Xs[(r + 3) * 64 + col]);
                float sil = s / (1.f + __expf(-s));
                out[e] = f2bf(sil);
            }
            int slot = g ^ (r & 7);
            *(bf16x8*)&As[r * 64 + slot * 8] = *(bf16x8*)out;
        }
        __syncthreads();
#pragma unroll
        for (int ks = 0; ks < 2; ks++) {
            bf16x8 af, wf[4];
            {
                int m = wm0 + ln15;
                int slot = (ks * 4 + q) ^ (m & 7);
                af = *(const bf16x8*)&As[m * 64 + slot * 8];
            }
#pragma unroll
            for (int jn = 0; jn < 4; jn++) {
                int n = wn0 + jn * 16 + ln15;
                int slot = (ks * 4 + q) ^ (n & 7);
                wf[jn] = *(const bf16x8*)&Ws[n * 64 + slot * 8];
            }
#pragma unroll
            for (int jn = 0; jn < 4; jn++)
                acc[jn] = __builtin_amdgcn_mfma_f32_16x16x32_bf16(
                    af, wf[jn], acc[jn], 0, 0, 0);
        }
    }
#pragma unroll
    for (int jn = 0; jn < 4; jn++) {
        int rr = row0 + wm0 + q * 4;
        int cc = wn0 + jn * 16 + ln15;
#pragma unroll
        for (int r = 0; r < 4; r++) {
            float v = acc[jn][r];
            if (cc < XDBL_W) xdbl[(size_t)(rr + r) * XDBL_W + cc] = v;
            if (cc < DT_RANK)  xdt[(size_t)(rr + r) * 64 + cc] = f2bf(v);
            else if (cc < 64)  xdt[(size_t)(rr + r) * 64 + cc] = 0;
        }
    }
}

// ---------------- scan with fused conv (rolling 4-tap window) ---------------
// 1024 threads: dsub = lane&15 (16 consecutive d), csub = lane>>4, 16 waves
// -> 64 chunks x 16 steps. u(l,d) = silu(conv(xz-x)) computed inline per step
// (1 new bf16 load + 3-reg rolling window). Hierarchical compose as before.
__global__ __launch_bounds__(1024) void scan2_kernel(
    const ushort* __restrict__ xzbf, const float* __restrict__ delta,
    const float* __restrict__ A_log, const float* __restrict__ xdbl,
    const float* __restrict__ Dskip, const float* __restrict__ cw,
    const float* __restrict__ cb, ushort* __restrict__ ybf)
{
    __shared__ float PL[16][SDN * 17];
    __shared__ float HL[16][SDN * 17];
    const int t = threadIdx.x;
    const int lane = t & 63;
    const int w = t >> 6;
    const int dsub = lane & 15;
    const int csub = lane >> 4;
    const int c = w * 4 + csub;       // chunk 0..63
    const int b = blockIdx.x / (D_INNER / SDN);
    const int d = (blockIdx.x % (D_INNER / SDN)) * SDN + dsub;

    float a2[D_STATE];
#pragma unroll
    for (int n = 0; n < D_STATE; n++)
        a2[n] = -__expf(A_log[d * D_STATE + n]) * 1.44269504f;

    const float cw0 = cw[d * 4 + 0], cw1 = cw[d * 4 + 1];
    const float cw2 = cw[d * 4 + 2], cw3 = cw[d * 4 + 3];
    const float cbv = cb[d];

    const size_t base = (size_t)b * SEQLEN * D_INNER + d;
    const float* dtp = delta + base;
    const ushort* xp = xzbf + (size_t)b * SEQLEN * (2 * D_INNER) + d;       // x half
    const ushort* zp = xp + D_INNER;                                        // z half
    const float* xrow = xdbl + (size_t)b * SEQLEN * XDBL_W;
    const int l0 = c * SCLEN;

    float h[D_STATE], P[D_STATE];
#pragma unroll
    for (int n = 0; n < D_STATE; n++) { h[n] = 0.f; P[n] = 1.f; }

    // conv rolling window prologue (x(l0-3), x(l0-2), x(l0-1))
    float a3c = 0.f, a2c = 0.f, a1c = 0.f;
    if (c > 0) {
        a3c = bf2f(xp[(size_t)(l0 - 3) * (2 * D_INNER)]);
        a2c = bf2f(xp[(size_t)(l0 - 2) * (2 * D_INNER)]);
        a1c = bf2f(xp[(size_t)(l0 - 1) * (2 * D_INNER)]);
    }

    // ---- phase 1: chunk transfer ----
    for (int i = 0; i < SCLEN; i++) {
        const int l = l0 + i;
        float dt = dtp[(size_t)l * D_INNER];
        float x0 = bf2f(xp[(size_t)l * (2 * D_INNER)]);
        float s = cbv + cw0 * a3c + cw1 * a2c + cw2 * a1c + cw3 * x0;
        a3c = a2c; a2c = a1c; a1c = x0;
        float uu = s / (1.f + __expf(-s));
        const float4* Bv = (const float4*)(xrow + (size_t)l * XDBL_W + DT_RANK);
        float4 q0 = Bv[0], q1 = Bv[1], q2 = Bv[2], q3 = Bv[3];
        float Bf[D_STATE] = {q0.x,q0.y,q0.z,q0.w, q1.x,q1.y,q1.z,q1.w,
                             q2.x,q2.y,q2.z,q2.w, q3.x,q3.y,q3.z,q3.w};
        float dtu = dt * uu;
#pragma unroll
        for (int n = 0; n < D_STATE; n++) {
            float e = __builtin_amdgcn_exp2f(dt * a2[n]);
            P[n] *= e;
            h[n] = e * h[n] + dtu * Bf[n];
        }
    }

    // ---- intra-wave inclusive scan over csub ----
#pragma unroll
    for (int n = 0; n < D_STATE; n++) {
        float Pp = __shfl(P[n], lane - 16, 64);
        float Hp = __shfl(h[n], lane - 16, 64);
        bool act = csub >= 1;
        h[n] = act ? P[n] * Hp + h[n] : h[n];
        P[n] = act ? P[n] * Pp : P[n];
    }
#pragma unroll
    for (int n = 0; n < D_STATE; n++) {
        float Pp = __shfl(P[n], lane - 32, 64);
        float Hp = __shfl(h[n], lane - 32, 64);
        bool act = csub >= 2;
        h[n] = act ? P[n] * Hp + h[n] : h[n];
        P[n] = act ? P[n] * Pp : P[n];
    }

    if (csub == 3) {
#pragma unroll
        for (int n = 0; n < D_STATE; n++) {
            PL[w][dsub * 17 + n] = P[n];
            HL[w][dsub * 17 + n] = h[n];
        }
    }
    __syncthreads();

    if (t < SDN * D_STATE) {
        const int d2 = t >> 4, n2 = t & 15;
        float hin = 0.f;
        for (int ww = 0; ww < 16; ww++) {
            float Pw = PL[ww][d2 * 17 + n2];
            float Hw = HL[ww][d2 * 17 + n2];
            HL[ww][d2 * 17 + n2] = hin;
            hin = Pw * hin + Hw;
        }
    }
    __syncthreads();

#pragma unroll
    for (int n = 0; n < D_STATE; n++) {
        float Win = HL[w][dsub * 17 + n];
        float Pe = __shfl(P[n], lane - 16, 64);
        float He = __shfl(h[n], lane - 16, 64);
        h[n] = (csub == 0) ? Win : Pe * Win + He;
    }

    // ---- phase 2: rescan with true h0, gate, emit y ----
    a3c = 0.f; a2c = 0.f; a1c = 0.f;
    if (c > 0) {
        a3c = bf2f(xp[(size_t)(l0 - 3) * (2 * D_INNER)]);
        a2c = bf2f(xp[(size_t)(l0 - 2) * (2 * D_INNER)]);
        a1c = bf2f(xp[(size_t)(l0 - 1) * (2 * D_INNER)]);
    }
    const float Dsk = Dskip[d];
    ushort* yp = ybf + base;
    for (int i = 0; i < SCLEN; i++) {
        const int l = l0 + i;
        float dt = dtp[(size_t)l * D_INNER];
        float x0 = bf2f(xp[(size_t)l * (2 * D_INNER)]);
        float s = cbv + cw0 * a3c + cw1 * a2c + cw2 * a1c + cw3 * x0;
        a3c = a2c; a2c = a1c; a1c = x0;
        float uu = s / (1.f + __expf(-s));
        float zz = bf2f(zp[(size_t)l * (2 * D_INNER)]);
        const float4* Bv = (const float4*)(xrow + (size_t)l * XDBL_W + DT_RANK);
        float4 q0 = Bv[0], q1 = Bv[1], q2 = Bv[2], q3 = Bv[3];
        float4 r0 = Bv[4], r1 = Bv[5], r2 = Bv[6], r3 = Bv[7];
        float Bf[D_STATE] = {q0.x,q0.y,q0.z,q0.w, q1.x,q1.y,q1.z,q1.w,
                             q2.x,q2.y,q2.z,q2.w, q3.x,q3.y,q3.z,q3.w};
        float Cf[D_STATE] = {r0.x,r0.y,r0.z,r0.w, r1.x,r1.y,r1.z,r1.w,
                             r2.x,r2.y,r2.z,r2.w, r3.x,r3.y,r3.z,r3.w};
        float dtu = dt * uu;
        float acc = 0.f;
#pragma unroll
        for (int n = 0; n < D_STATE; n++) {
            float e = __builtin_amdgcn_exp2f(dt * a2[n]);
            h[n] = e * h[n] + dtu * Bf[n];
            acc += h[n] * Cf[n];
        }
        float yy = acc + uu * Dsk;
        float ee = __builtin_amdgcn_exp2f(-zz * 1.44269504f);
        float sil = zz * __builtin_amdgcn_rcpf(1.f + ee);
        yp[(size_t)l * D_INNER] = f2bf(yy * sil);
    }
}

extern "C" void kernel_launch(void* const* d_in, const int* in_sizes, int n_in,
                              void* d_out, int out_size, void* d_ws, size_t ws_size,
                              hipStream_t stream)
{
    const float* hs        = (const float*)d_in[0];
    const float* norm_w    = (const float*)d_in[1];
    const float* in_proj_w = (const float*)d_in[2];
    const float* conv_w    = (const float*)d_in[3];
    const float* conv_b    = (const float*)d_in[4];
    const float* x_proj_w  = (const float*)d_in[5];
    const float* dt_proj_w = (const float*)d_in[6];
    const float* dt_proj_b = (const float*)d_in[7];
    const float* A_log     = (const float*)d_in[8];
    const float* D_skip    = (const float*)d_in[9];
    const float* out_proj_w= (const float*)d_in[10];
    const float* norm_f_w  = (const float*)d_in[11];

    float* ws = (float*)d_ws;
    float* residual = ws;                                   // 2048*768
    float* hidden   = residual + NROWS * D_MODEL;           // 2048*768
    float* xdbl     = hidden + NROWS * D_MODEL;             // 2048*80
    float* delta    = xdbl + NROWS * XDBL_W;                // 2048*1536
    ushort* xzbf    = (ushort*)(delta + NROWS * D_INNER);   // 2048*3072
    ushort* normbf  = xzbf + (size_t)NROWS * 2 * D_INNER;   // 2048*768
    ushort* ybf     = normbf + NROWS * D_MODEL;             // 2048*1536
    ushort* xdtbf   = ybf + NROWS * D_INNER;                // 2048*64
    ushort* win_bf  = xdtbf + NROWS * 64;                   // 3*3072*768
    ushort* wout_bf = win_bf + (size_t)N_LAYER * 2 * D_INNER * D_MODEL;
    ushort* xw_pad  = wout_bf + (size_t)N_LAYER * D_MODEL * D_INNER; // 3*128*1536
    ushort* dtw_pad = xw_pad + (size_t)N_LAYER * 128 * 1536;          // 3*1536*64

    // all weight conversions in one dispatch
    cvt_all_kernel<<<(CVT_TOT + 255) / 256, 256, 0, stream>>>(
        in_proj_w, out_proj_w, x_proj_w, dt_proj_w,
        win_bf, wout_bf, xw_pad, dtw_pad);

    for (int i = 0; i < N_LAYER; i++) {
        add_rmsnorm_kernel<<<NROWS, 256, 0, stream>>>(
            i == 0 ? hs : hidden, i == 0 ? nullptr : residual,
            norm_w + i * D_MODEL, residual, nullptr, normbf);
        // in_proj: 2048x3072, K=768 — 128x128 tiles, 384 blocks, bf16 out
        gemm_mfma_kernel<128, 128, 0, 1><<<dim3(2 * D_INNER / 128, NROWS / 128), 256, 0, stream>>>(
            normbf, win_bf + (size_t)i * 2 * D_INNER * D_MODEL, nullptr,
            xzbf, 2 * D_INNER, 2 * D_INNER, NROWS, D_MODEL);
        // x_proj with fused conv+SiLU: dual out f32 xdbl + bf16 xdt
        xproj_conv_kernel<<<dim3(1, NROWS / 32), 256, 0, stream>>>(
            xzbf, xw_pad + (size_t)i * 128 * 1536,
            conv_w + i * D_INNER * D_CONV, conv_b + i * D_INNER,
            xdbl, xdtbf);
        // dt_proj: 2048x1536, K=64(pad) — softplus epilogue, 384 blocks
        gemm_mfma_kernel<64, 128, 1, 0><<<dim3(D_INNER / 128, NROWS / 64), 256, 0, stream>>>(
            xdtbf, dtw_pad + (size_t)i * 1536 * 64, dt_proj_b + i * D_INNER,
            delta, D_INNER, D_INNER, NROWS, 64);
        // scan with fused conv (rolling window)
        scan2_kernel<<<BATCH * (D_INNER / SDN), 1024, 0, stream>>>(
            xzbf, delta, A_log + (size_t)i * D_INNER * D_STATE, xdbl,
            D_skip + i * D_INNER, conv_w + i * D_INNER * D_CONV,
            conv_b + i * D_INNER, ybf);
        // out_proj: 2048x768, K=1536
        gemm_mfma_kernel<64, 64, 0, 0><<<dim3(D_MODEL / 64, NROWS / 64), 256, 0, stream>>>(
            ybf, wout_bf + (size_t)i * D_MODEL * D_INNER, nullptr,
            hidden, D_MODEL, D_MODEL, NROWS, D_INNER);
    }
    add_rmsnorm_kernel<<<NROWS, 256, 0, stream>>>(
        hidden, residual, norm_f_w, nullptr, (float*)d_out, nullptr);
}

// Round 11
// 524.102 us; speedup vs baseline: 1.1938x; 1.1938x over previous
//
#include <hip/hip_runtime.h>
#include <math.h>

#define D_MODEL 768
#define D_INNER 1536
#define D_STATE 16
#define D_CONV 4
#define DT_RANK 48
#define N_LAYER 3
#define BATCH 2
#define SEQLEN 1024
#define NROWS (BATCH * SEQLEN)   // 2048
#define XDBL_W (DT_RANK + 2 * D_STATE)  // 80
#define EPS 1e-5f

#define SCLEN 16
#define SDN 16                   // d-channels per scan block

typedef short bf16x8 __attribute__((ext_vector_type(8)));
typedef float f32x4 __attribute__((ext_vector_type(4)));

__device__ __forceinline__ ushort f2bf(float x) {
    union { float f; uint u; } v; v.f = x;
    uint r = v.u + 0x7fff + ((v.u >> 16) & 1);   // RNE
    return (ushort)(r >> 16);
}
__device__ __forceinline__ float bf2f(ushort x) {
    union { uint u; float f; } v; v.u = ((uint)x) << 16;
    return v.f;
}

__device__ __forceinline__ void gload_lds16(const void* g, void* l) {
    __builtin_amdgcn_global_load_lds(
        (const __attribute__((address_space(1))) unsigned int*)g,
        (__attribute__((address_space(3))) unsigned int*)l, 16, 0, 0);
}

// ---------------- all weight conversions in ONE dispatch ----------------
#define CVT_N0 (3 * 3072 * 768 / 4)
#define CVT_N1 (3 * 768 * 1536 / 4)
#define CVT_N2 (3 * 128 * 1536 / 4)
#define CVT_N3 (3 * 1536 * 64 / 4)
#define CVT_C1 (CVT_N0)
#define CVT_C2 (CVT_C1 + CVT_N1)
#define CVT_C3 (CVT_C2 + CVT_N2)
#define CVT_TOT (CVT_C3 + CVT_N3)

__global__ __launch_bounds__(256) void cvt_all_kernel(
    const float* __restrict__ w_in, const float* __restrict__ w_out,
    const float* __restrict__ w_x, const float* __restrict__ w_dt,
    ushort* __restrict__ d_in, ushort* __restrict__ d_out,
    ushort* __restrict__ d_x, ushort* __restrict__ d_dt)
{
    int i = blockIdx.x * 256 + threadIdx.x;
    if (i < CVT_C1) {
        float4 v = ((const float4*)w_in)[i];
        ushort4 o; o.x = f2bf(v.x); o.y = f2bf(v.y); o.z = f2bf(v.z); o.w = f2bf(v.w);
        ((ushort4*)d_in)[i] = o;
    } else if (i < CVT_C2) {
        int j = i - CVT_C1;
        float4 v = ((const float4*)w_out)[j];
        ushort4 o; o.x = f2bf(v.x); o.y = f2bf(v.y); o.z = f2bf(v.z); o.w = f2bf(v.w);
        ((ushort4*)d_out)[j] = o;
    } else if (i < CVT_C3) {
        int j = i - CVT_C2;
        const int per = 128 * 1536 / 4;
        int li = j / per, rem = j - li * per;
        int r = (rem * 4) / 1536, c = (rem * 4) % 1536;
        ushort4 o = make_ushort4(0, 0, 0, 0);
        if (r < XDBL_W) {
            const float* s = w_x + ((size_t)li * XDBL_W + r) * 1536 + c;
            o.x = f2bf(s[0]); o.y = f2bf(s[1]); o.z = f2bf(s[2]); o.w = f2bf(s[3]);
        }
        ((ushort4*)d_x)[j] = o;
    } else if (i < CVT_TOT) {
        int j = i - CVT_C3;
        const int per = 1536 * 64 / 4;
        int li = j / per, rem = j - li * per;
        int r = (rem * 4) / 64, c = (rem * 4) % 64;
        ushort4 o = make_ushort4(0, 0, 0, 0);
        if (c < DT_RANK) {
            const float* s = w_dt + ((size_t)li * 1536 + r) * DT_RANK + c;
            o.x = f2bf(s[0]); o.y = f2bf(s[1]); o.z = f2bf(s[2]); o.w = f2bf(s[3]);
        }
        ((ushort4*)d_dt)[j] = o;
    }
}

// ---------------- add + rmsnorm ----------------
__global__ __launch_bounds__(256) void add_rmsnorm_kernel(
    const float* __restrict__ x, const float* __restrict__ res_in,
    const float* __restrict__ w, float* __restrict__ res_out,
    float* __restrict__ normed_f32, ushort* __restrict__ normed_bf)
{
    int row = blockIdx.x;
    int tid = threadIdx.x;
    const float* xr = x + row * D_MODEL;
    float v[3];
    float ss = 0.f;
#pragma unroll
    for (int i = 0; i < 3; i++) {
        int c = tid + i * 256;
        float t = xr[c];
        if (res_in) t += res_in[row * D_MODEL + c];
        v[i] = t;
        ss += t * t;
    }
    for (int off = 32; off; off >>= 1) ss += __shfl_xor(ss, off, 64);
    __shared__ float red[4];
    if ((tid & 63) == 0) red[tid >> 6] = ss;
    __syncthreads();
    float tot = red[0] + red[1] + red[2] + red[3];
    float scale = rsqrtf(tot * (1.f / D_MODEL) + EPS);
#pragma unroll
    for (int i = 0; i < 3; i++) {
        int c = tid + i * 256;
        if (res_out) res_out[row * D_MODEL + c] = v[i];
        float o = v[i] * scale * w[c];
        if (normed_f32) normed_f32[row * D_MODEL + c] = o;
        if (normed_bf)  normed_bf[row * D_MODEL + c] = f2bf(o);
    }
}

// ---------------- bf16 MFMA GEMM: C[M,N] = A[M,K] @ W[N,K]^T ----------------
// EPI: 0 none (f32 or bf16 out per OUTBF), 1 softplus(acc+bias[n]) f32 out,
// 2 dual-out: f32 to Cv (ldc, cc<Nout) AND bf16 to C2 (ld 64, cc<48; zeros
// for 48<=cc<64).
template <int BM, int BN, int EPI, int OUTBF>
__global__ __launch_bounds__(256) void gemm_mfma_kernel(
    const ushort* __restrict__ A, const ushort* __restrict__ W,
    const float* __restrict__ bias, void* __restrict__ Cv,
    ushort* __restrict__ C2, int ldc, int Nout, int M, int K)
{
    constexpr int TM = BM / 32;
    constexpr int TN = BN / 32;
    __shared__ __attribute__((aligned(16))) ushort As[BM * 64];
    __shared__ __attribute__((aligned(16))) ushort Ws[BN * 64];
    const int t = threadIdx.x;
    const int lane = t & 63, w = t >> 6;
    const int ln15 = lane & 15, q = lane >> 4;
    const int row0 = blockIdx.y * BM, col0 = blockIdx.x * BN;
    const int wm0 = (w & 1) * (BM / 2), wn0 = (w >> 1) * (BN / 2);

    float* Cf = (float*)Cv;
    ushort* Cb = (ushort*)Cv;

    f32x4 acc[TM][TN];
#pragma unroll
    for (int i = 0; i < TM; i++)
#pragma unroll
        for (int j = 0; j < TN; j++) acc[i][j] = (f32x4){0.f, 0.f, 0.f, 0.f};

    for (int k0 = 0; k0 < K; k0 += 64) {
        __syncthreads();
#pragma unroll
        for (int i = 0; i < BM / 32; i++) {
            int p = (i * 4 + w) * 64 + lane;
            int r = p >> 3, s = p & 7;
            int g = s ^ (r & 7);
            gload_lds16(A + (size_t)(row0 + r) * K + k0 + g * 8, &As[p * 8]);
        }
#pragma unroll
        for (int i = 0; i < BN / 32; i++) {
            int p = (i * 4 + w) * 64 + lane;
            int r = p >> 3, s = p & 7;
            int g = s ^ (r & 7);
            gload_lds16(W + (size_t)(col0 + r) * K + k0 + g * 8, &Ws[p * 8]);
        }
        __syncthreads();
#pragma unroll
        for (int ks = 0; ks < 2; ks++) {
            bf16x8 af[TM], wf[TN];
#pragma unroll
            for (int im = 0; im < TM; im++) {
                int m = wm0 + im * 16 + ln15;
                int slot = (ks * 4 + q) ^ (m & 7);
                af[im] = *(const bf16x8*)&As[m * 64 + slot * 8];
            }
#pragma unroll
            for (int jn = 0; jn < TN; jn++) {
                int n = wn0 + jn * 16 + ln15;
                int slot = (ks * 4 + q) ^ (n & 7);
                wf[jn] = *(const bf16x8*)&Ws[n * 64 + slot * 8];
            }
#pragma unroll
            for (int im = 0; im < TM; im++)
#pragma unroll
                for (int jn = 0; jn < TN; jn++)
                    acc[im][jn] = __builtin_amdgcn_mfma_f32_16x16x32_bf16(
                        af[im], wf[jn], acc[im][jn], 0, 0, 0);
        }
    }
#pragma unroll
    for (int im = 0; im < TM; im++) {
#pragma unroll
        for (int jn = 0; jn < TN; jn++) {
            int rr = row0 + wm0 + im * 16 + q * 4;
            int cc = col0 + wn0 + jn * 16 + ln15;
#pragma unroll
            for (int r = 0; r < 4; r++) {
                float v = acc[im][jn][r];
                if (EPI == 2) {
                    if (cc < Nout) Cf[(size_t)(rr + r) * ldc + cc] = v;
                    if (cc < DT_RANK)  C2[(size_t)(rr + r) * 64 + cc] = f2bf(v);
                    else if (cc < 64)  C2[(size_t)(rr + r) * 64 + cc] = 0;
                } else if (cc < Nout) {
                    if (EPI == 1) {
                        v += bias[cc];
                        v = (v > 20.f) ? v : log1pf(__expf(v));
                    }
                    if (OUTBF) Cb[(size_t)(rr + r) * ldc + cc] = f2bf(v);
                    else       Cf[(size_t)(rr + r) * ldc + cc] = v;
                }
            }
        }
    }
}

// ---------------- depthwise causal conv1d (k=4) + SiLU (bf16 in/out) -------
__global__ __launch_bounds__(256) void conv_silu_kernel(
    const ushort* __restrict__ xzbf, const float* __restrict__ cw,
    const float* __restrict__ cb, ushort* __restrict__ out_bf)
{
    int idx = blockIdx.x * 256 + threadIdx.x;
    int d = idx % D_INNER;
    int bl = idx / D_INNER;
    int l = bl % SEQLEN;
    float s = cb[d];
    const ushort* xp = xzbf + (size_t)bl * (2 * D_INNER) + d;
#pragma unroll
    for (int k = 0; k < D_CONV; k++) {
        int ls = l - (D_CONV - 1) + k;
        if (ls >= 0) s += cw[d * D_CONV + k] * bf2f(xp[(k - (D_CONV - 1)) * (2 * D_INNER)]);
    }
    float sil = s / (1.f + __expf(-s));
    out_bf[(size_t)bl * D_INNER + d] = f2bf(sil);
}

// ---------------- coalesced chunked selective scan ----------------
// 1024 threads: dsub = lane&15 (16 consecutive d), csub = lane>>4 (4 chunks/
// wave), 16 waves -> 64 chunks. Intra-wave shfl scan + LDS cross-wave serial
// compose. Phase loops unrolled x4 so the compiler hoists ~4 steps of
// independent loads (raises memory-level parallelism; round-6 counters showed
// this kernel fetch-bound at only 1.77 TB/s).
__global__ __launch_bounds__(1024) void scan2_kernel(
    const ushort* __restrict__ ubf, const float* __restrict__ delta,
    const float* __restrict__ A_log, const float* __restrict__ xdbl,
    const float* __restrict__ Dskip, const ushort* __restrict__ xzbf,
    ushort* __restrict__ ybf)
{
    __shared__ float PL[16][SDN * 17];
    __shared__ float HL[16][SDN * 17];
    const int t = threadIdx.x;
    const int lane = t & 63;
    const int w = t >> 6;             // wave 0..15
    const int dsub = lane & 15;
    const int csub = lane >> 4;       // 0..3
    const int c = w * 4 + csub;       // chunk 0..63
    const int b = blockIdx.x / (D_INNER / SDN);
    const int d = (blockIdx.x % (D_INNER / SDN)) * SDN + dsub;

    float a2[D_STATE];
#pragma unroll
    for (int n = 0; n < D_STATE; n++)
        a2[n] = -__expf(A_log[d * D_STATE + n]) * 1.44269504f;

    const size_t base = (size_t)b * SEQLEN * D_INNER + d;
    const float* dtp = delta + base;
    const ushort* up = ubf + base;
    const float* xrow = xdbl + (size_t)b * SEQLEN * XDBL_W;
    const int l0 = c * SCLEN;

    float h[D_STATE], P[D_STATE];
#pragma unroll
    for (int n = 0; n < D_STATE; n++) { h[n] = 0.f; P[n] = 1.f; }

    // ---- phase 1: chunk transfer ----
#pragma unroll 4
    for (int i = 0; i < SCLEN; i++) {
        const int l = l0 + i;
        float dt = dtp[(size_t)l * D_INNER];
        float uu = bf2f(up[(size_t)l * D_INNER]);
        const float4* Bv = (const float4*)(xrow + (size_t)l * XDBL_W + DT_RANK);
        float4 q0 = Bv[0], q1 = Bv[1], q2 = Bv[2], q3 = Bv[3];
        float Bf[D_STATE] = {q0.x,q0.y,q0.z,q0.w, q1.x,q1.y,q1.z,q1.w,
                             q2.x,q2.y,q2.z,q2.w, q3.x,q3.y,q3.z,q3.w};
        float dtu = dt * uu;
#pragma unroll
        for (int n = 0; n < D_STATE; n++) {
            float e = __builtin_amdgcn_exp2f(dt * a2[n]);
            P[n] *= e;
            h[n] = e * h[n] + dtu * Bf[n];
        }
    }

    // ---- intra-wave inclusive scan over csub ----
#pragma unroll
    for (int n = 0; n < D_STATE; n++) {
        float Pp = __shfl(P[n], lane - 16, 64);
        float Hp = __shfl(h[n], lane - 16, 64);
        bool act = csub >= 1;
        h[n] = act ? P[n] * Hp + h[n] : h[n];
        P[n] = act ? P[n] * Pp : P[n];
    }
#pragma unroll
    for (int n = 0; n < D_STATE; n++) {
        float Pp = __shfl(P[n], lane - 32, 64);
        float Hp = __shfl(h[n], lane - 32, 64);
        bool act = csub >= 2;
        h[n] = act ? P[n] * Hp + h[n] : h[n];
        P[n] = act ? P[n] * Pp : P[n];
    }

    if (csub == 3) {
#pragma unroll
        for (int n = 0; n < D_STATE; n++) {
            PL[w][dsub * 17 + n] = P[n];
            HL[w][dsub * 17 + n] = h[n];
        }
    }
    __syncthreads();

    if (t < SDN * D_STATE) {
        const int d2 = t >> 4, n2 = t & 15;
        float hin = 0.f;
        for (int ww = 0; ww < 16; ww++) {
            float Pw = PL[ww][d2 * 17 + n2];
            float Hw = HL[ww][d2 * 17 + n2];
            HL[ww][d2 * 17 + n2] = hin;
            hin = Pw * hin + Hw;
        }
    }
    __syncthreads();

#pragma unroll
    for (int n = 0; n < D_STATE; n++) {
        float Win = HL[w][dsub * 17 + n];
        float Pe = __shfl(P[n], lane - 16, 64);
        float He = __shfl(h[n], lane - 16, 64);
        h[n] = (csub == 0) ? Win : Pe * Win + He;
    }

    // ---- phase 2: rescan with true h0, gate, emit y ----
    const float Dsk = Dskip[d];
    const ushort* zp = xzbf + (size_t)b * SEQLEN * (2 * D_INNER) + D_INNER + d;
    ushort* yp = ybf + base;
#pragma unroll 4
    for (int i = 0; i < SCLEN; i++) {
        const int l = l0 + i;
        float dt = dtp[(size_t)l * D_INNER];
        float uu = bf2f(up[(size_t)l * D_INNER]);
        float zz = bf2f(zp[(size_t)l * (2 * D_INNER)]);
        const float4* Bv = (const float4*)(xrow + (size_t)l * XDBL_W + DT_RANK);
        float4 q0 = Bv[0], q1 = Bv[1], q2 = Bv[2], q3 = Bv[3];
        float4 r0 = Bv[4], r1 = Bv[5], r2 = Bv[6], r3 = Bv[7];
        float Bf[D_STATE] = {q0.x,q0.y,q0.z,q0.w, q1.x,q1.y,q1.z,q1.w,
                             q2.x,q2.y,q2.z,q2.w, q3.x,q3.y,q3.z,q3.w};
        float Cf[D_STATE] = {r0.x,r0.y,r0.z,r0.w, r1.x,r1.y,r1.z,r1.w,
                             r2.x,r2.y,r2.z,r2.w, r3.x,r3.y,r3.z,r3.w};
        float dtu = dt * uu;
        float acc = 0.f;
#pragma unroll
        for (int n = 0; n < D_STATE; n++) {
            float e = __builtin_amdgcn_exp2f(dt * a2[n]);
            h[n] = e * h[n] + dtu * Bf[n];
            acc += h[n] * Cf[n];
        }
        float yy = acc + uu * Dsk;
        float ee = __builtin_amdgcn_exp2f(-zz * 1.44269504f);
        float sil = zz * __builtin_amdgcn_rcpf(1.f + ee);
        yp[(size_t)l * D_INNER] = f2bf(yy * sil);
    }
}

extern "C" void kernel_launch(void* const* d_in, const int* in_sizes, int n_in,
                              void* d_out, int out_size, void* d_ws, size_t ws_size,
                              hipStream_t stream)
{
    const float* hs        = (const float*)d_in[0];
    const float* norm_w    = (const float*)d_in[1];
    const float* in_proj_w = (const float*)d_in[2];
    const float* conv_w    = (const float*)d_in[3];
    const float* conv_b    = (const float*)d_in[4];
    const float* x_proj_w  = (const float*)d_in[5];
    const float* dt_proj_w = (const float*)d_in[6];
    const float* dt_proj_b = (const float*)d_in[7];
    const float* A_log     = (const float*)d_in[8];
    const float* D_skip    = (const float*)d_in[9];
    const float* out_proj_w= (const float*)d_in[10];
    const float* norm_f_w  = (const float*)d_in[11];

    float* ws = (float*)d_ws;
    float* residual = ws;                                   // 2048*768
    float* hidden   = residual + NROWS * D_MODEL;           // 2048*768
    float* xdbl     = hidden + NROWS * D_MODEL;             // 2048*80
    float* delta    = xdbl + NROWS * XDBL_W;                // 2048*1536
    ushort* xzbf    = (ushort*)(delta + NROWS * D_INNER);   // 2048*3072
    ushort* normbf  = xzbf + (size_t)NROWS * 2 * D_INNER;   // 2048*768
    ushort* ybf     = normbf + NROWS * D_MODEL;             // 2048*1536
    ushort* xconvbf = ybf + NROWS * D_INNER;                // 2048*1536
    ushort* xdtbf   = xconvbf + NROWS * D_INNER;            // 2048*64
    ushort* win_bf  = xdtbf + NROWS * 64;                   // 3*3072*768
    ushort* wout_bf = win_bf + (size_t)N_LAYER * 2 * D_INNER * D_MODEL;
    ushort* xw_pad  = wout_bf + (size_t)N_LAYER * D_MODEL * D_INNER; // 3*128*1536
    ushort* dtw_pad = xw_pad + (size_t)N_LAYER * 128 * 1536;          // 3*1536*64

    // all weight conversions in one dispatch
    cvt_all_kernel<<<(CVT_TOT + 255) / 256, 256, 0, stream>>>(
        in_proj_w, out_proj_w, x_proj_w, dt_proj_w,
        win_bf, wout_bf, xw_pad, dtw_pad);

    for (int i = 0; i < N_LAYER; i++) {
        add_rmsnorm_kernel<<<NROWS, 256, 0, stream>>>(
            i == 0 ? hs : hidden, i == 0 ? nullptr : residual,
            norm_w + i * D_MODEL, residual, nullptr, normbf);
        // in_proj: 2048x3072, K=768 — bf16 out, 768 blocks
        gemm_mfma_kernel<64, 128, 0, 1><<<dim3(2 * D_INNER / 128, NROWS / 64), 256, 0, stream>>>(
            normbf, win_bf + (size_t)i * 2 * D_INNER * D_MODEL, nullptr,
            xzbf, nullptr, 2 * D_INNER, 2 * D_INNER, NROWS, D_MODEL);
        conv_silu_kernel<<<NROWS * D_INNER / 256, 256, 0, stream>>>(
            xzbf, conv_w + i * D_INNER * D_CONV, conv_b + i * D_INNER, xconvbf);
        // x_proj: 2048x80(pad128), K=1536 — dual out (f32 xdbl + bf16 xdt)
        gemm_mfma_kernel<32, 128, 2, 0><<<dim3(1, NROWS / 32), 256, 0, stream>>>(
            xconvbf, xw_pad + (size_t)i * 128 * 1536, nullptr,
            xdbl, xdtbf, XDBL_W, XDBL_W, NROWS, D_INNER);
        // dt_proj: 2048x1536, K=64(pad) — softplus epilogue, 384 blocks
        gemm_mfma_kernel<64, 128, 1, 0><<<dim3(D_INNER / 128, NROWS / 64), 256, 0, stream>>>(
            xdtbf, dtw_pad + (size_t)i * 1536 * 64, dt_proj_b + i * D_INNER,
            delta, nullptr, D_INNER, D_INNER, NROWS, 64);
        // scan: proven single-dispatch form (bf16 u/z) + unroll-4 MLP
        scan2_kernel<<<BATCH * (D_INNER / SDN), 1024, 0, stream>>>(
            xconvbf, delta, A_log + (size_t)i * D_INNER * D_STATE, xdbl,
            D_skip + i * D_INNER, xzbf, ybf);
        // out_proj: 2048x768, K=1536
        gemm_mfma_kernel<64, 64, 0, 0><<<dim3(D_MODEL / 64, NROWS / 64), 256, 0, stream>>>(
            ybf, wout_bf + (size_t)i * D_MODEL * D_INNER, nullptr,
            hidden, nullptr, D_MODEL, D_MODEL, NROWS, D_INNER);
    }
    add_rmsnorm_kernel<<<NROWS, 256, 0, stream>>>(
        hidden, residual, norm_f_w, nullptr, (float*)d_out, nullptr);
}